// Round 7
// baseline (981.596 us; speedup 1.0000x reference)
//
#include <hip/hip_runtime.h>
#include <hip/hip_bf16.h>
#include <stdint.h>

typedef __attribute__((ext_vector_type(8))) __bf16 bf16x8;
typedef __attribute__((ext_vector_type(4))) float f32x4;

#define BM 128
#define BN 128
#define BK 64

__device__ inline void gload_lds16(const void* g, void* l) {
    __builtin_amdgcn_global_load_lds(
        (const __attribute__((address_space(1))) uint32_t*)g,
        (__attribute__((address_space(3))) uint32_t*)l, 16, 0, 0);
}

// ---------------- pass 1a: X f32 -> bf16 ----------------
__global__ __launch_bounds__(256)
void cvt_x(const float* __restrict__ X, __bf16* __restrict__ Xb, size_t n8) {
    for (size_t i = blockIdx.x * 256ull + threadIdx.x; i < n8; i += (size_t)gridDim.x * 256ull) {
        const float4 x0 = *(const float4*)(X + i * 8);
        const float4 x1 = *(const float4*)(X + i * 8 + 4);
        bf16x8 v;
        v[0] = (__bf16)x0.x; v[1] = (__bf16)x0.y; v[2] = (__bf16)x0.z; v[3] = (__bf16)x0.w;
        v[4] = (__bf16)x1.x; v[5] = (__bf16)x1.y; v[6] = (__bf16)x1.z; v[7] = (__bf16)x1.w;
        *((bf16x8*)(Xb + i * 8)) = v;
    }
}

// ---------------- pass 1b: dequant W -> bf16 [N][K] ----------------
__global__ __launch_bounds__(128)
void dequant_w(const int* __restrict__ QW, const int* __restrict__ QZ,
               const float* __restrict__ S, __bf16* __restrict__ W, int N, int K) {
    const int PQ = K >> 3, NG = K >> 7, ZS = (NG + 7) >> 3;
    const int o = blockIdx.x;
    const int c = threadIdx.x;            // 0..K/32-1
    const int k0 = c * 32;
    const int g = k0 >> 7;
    const int zq = (QZ[(size_t)o * ZS + (g >> 3)] >> ((g & 7) * 4)) & 15;
    const float sf = S[(size_t)o * NG + g];
    const float zs = (float)zq * sf;
    const int4 qv = *(const int4*)(QW + (size_t)o * PQ + c * 4);
    const int vs[4] = {qv.x, qv.y, qv.z, qv.w};
#pragma unroll
    for (int w = 0; w < 4; ++w) {
        const int v = vs[w];
        bf16x8 wv;
#pragma unroll
        for (int j = 0; j < 8; ++j) {
            const float q = (float)((v >> (4 * j)) & 15);
            wv[j] = (__bf16)(q * sf - zs);
        }
        *((bf16x8*)(W + (size_t)o * K + k0 + w * 8)) = wv;
    }
}

// ---------------- pass 2: 256x256 8-phase bf16 GEMM (m201-style) ----------------
// 512 threads = 8 waves (2 wm x 4 wn); per-wave output 128x64 (acc[8][4]).
// LDS 128 KB: A/B x 2 K-tile parities x 2 K-halves, each half = [256 rows][32 cols]
// bf16 (16 KB, 64B rows). Zero-conflict chunk-XOR swizzle (pre-swizzled global
// source, linear gload_lds dest, swizzled reads) - proven 0 conflicts in r6.
// Iteration = 2 K-tiles (t0 par0, t0+1 par1) x 4 phases each:
//   ph: [8 or 4 ds_reads | stage half-tile] -> barrier -> lgkm0 -> 16 MFMA -> barrier
// Stage schedule (FIFO-audited): ph1: par1-kh1<-t0+1; ph3: A par0-kh0<-t0+2;
// ph4: B par0-kh0 + vmcnt(4); ph5: par0-kh1<-t0+2; ph7: A par1-kh0<-t0+3;
// ph8: B par1-kh0 + vmcnt(4). Gates retire exactly what the next 4 phases read.
__global__ __launch_bounds__(512, 2)
void gemm_8ph(const __bf16* __restrict__ A, const __bf16* __restrict__ B,
              const float* __restrict__ Bi, float* __restrict__ Out,
              int M, int N, int K) {
    __shared__ __align__(16) char lds[131072];

    const int tid  = threadIdx.x;
    const int lane = tid & 63;
    const int wid  = tid >> 6;
    const int wm   = wid >> 2;   // 0..1
    const int wn   = wid & 3;    // 0..3

    int bid = blockIdx.x;
    {
        const int nwg = gridDim.x;
        if ((nwg & 7) == 0) {
            const int cpx = nwg >> 3;
            bid = (bid & 7) * cpx + (bid >> 3);
        }
    }
    const int nbm  = M / 256;
    const int brow = (bid % nbm) * 256;     // col-major: B-panel L2-resident
    const int bcol = (bid / nbm) * 256;

    // staging: half = 1024 slots of 16B; thread t -> slots t, t+512.
    // slot s: row = s>>2, c_lds = s&3; global chunk c_g = (s&3) ^ ((s>>3)&3).
    const int ra0 = tid >> 2, ra1 = ra0 + 128;
    const int ca  = (tid & 3) ^ ((tid >> 3) & 3);
    const __bf16* gA0 = A + (size_t)(brow + ra0) * K + ca * 8;
    const __bf16* gA1 = A + (size_t)(brow + ra1) * K + ca * 8;
    const __bf16* gB0 = B + (size_t)(bcol + ra0) * K + ca * 8;
    const __bf16* gB1 = B + (size_t)(bcol + ra1) * K + ca * 8;
    const int lb0 = wid * 1024;
    const int lb1 = wid * 1024 + 8192;

    // fragment reads: row byte = row*64 + ((q ^ ((row>>1)&3))*16), q = lane>>4
    const int rA = lane & 15;
    const int chunkoff = ((lane >> 4) ^ ((rA >> 1) & 3)) * 16;

    f32x4 acc[8][4];
#pragma unroll
    for (int i = 0; i < 8; ++i)
#pragma unroll
        for (int j = 0; j < 4; ++j)
            acc[i][j] = {0.f, 0.f, 0.f, 0.f};

#define LDSA(P_, H_) (lds + ((P_) * 2 + (H_)) * 16384)
#define LDSB(P_, H_) (lds + 65536 + ((P_) * 2 + (H_)) * 16384)
#define RD(BASE_, ROW_) (*(const bf16x8*)((BASE_) + (ROW_) * 64 + chunkoff))
#define SBAR __builtin_amdgcn_sched_barrier(0)
#define GATE(N_) asm volatile("s_waitcnt vmcnt(" #N_ ")" ::: "memory")

#define STA(P_, H_, T_)                                                         \
    do {                                                                        \
        gload_lds16(gA0 + (size_t)(T_) * 64 + (H_) * 32, LDSA(P_, H_) + lb0);   \
        gload_lds16(gA1 + (size_t)(T_) * 64 + (H_) * 32, LDSA(P_, H_) + lb1);   \
    } while (0)
#define STB(P_, H_, T_)                                                         \
    do {                                                                        \
        gload_lds16(gB0 + (size_t)(T_) * 64 + (H_) * 32, LDSB(P_, H_) + lb0);   \
        gload_lds16(gB1 + (size_t)(T_) * 64 + (H_) * 32, LDSB(P_, H_) + lb1);   \
    } while (0)

#define MFMA16(F0_, F1_, F2_, F3_, RB_)                                                            \
    do {                                                                                           \
        acc[RB_ + 0][0] = __builtin_amdgcn_mfma_f32_16x16x32_bf16(F0_, bf0, acc[RB_ + 0][0], 0, 0, 0); \
        acc[RB_ + 0][1] = __builtin_amdgcn_mfma_f32_16x16x32_bf16(F0_, bf1, acc[RB_ + 0][1], 0, 0, 0); \
        acc[RB_ + 0][2] = __builtin_amdgcn_mfma_f32_16x16x32_bf16(F0_, bf2, acc[RB_ + 0][2], 0, 0, 0); \
        acc[RB_ + 0][3] = __builtin_amdgcn_mfma_f32_16x16x32_bf16(F0_, bf3, acc[RB_ + 0][3], 0, 0, 0); \
        acc[RB_ + 1][0] = __builtin_amdgcn_mfma_f32_16x16x32_bf16(F1_, bf0, acc[RB_ + 1][0], 0, 0, 0); \
        acc[RB_ + 1][1] = __builtin_amdgcn_mfma_f32_16x16x32_bf16(F1_, bf1, acc[RB_ + 1][1], 0, 0, 0); \
        acc[RB_ + 1][2] = __builtin_amdgcn_mfma_f32_16x16x32_bf16(F1_, bf2, acc[RB_ + 1][2], 0, 0, 0); \
        acc[RB_ + 1][3] = __builtin_amdgcn_mfma_f32_16x16x32_bf16(F1_, bf3, acc[RB_ + 1][3], 0, 0, 0); \
        acc[RB_ + 2][0] = __builtin_amdgcn_mfma_f32_16x16x32_bf16(F2_, bf0, acc[RB_ + 2][0], 0, 0, 0); \
        acc[RB_ + 2][1] = __builtin_amdgcn_mfma_f32_16x16x32_bf16(F2_, bf1, acc[RB_ + 2][1], 0, 0, 0); \
        acc[RB_ + 2][2] = __builtin_amdgcn_mfma_f32_16x16x32_bf16(F2_, bf2, acc[RB_ + 2][2], 0, 0, 0); \
        acc[RB_ + 2][3] = __builtin_amdgcn_mfma_f32_16x16x32_bf16(F2_, bf3, acc[RB_ + 2][3], 0, 0, 0); \
        acc[RB_ + 3][0] = __builtin_amdgcn_mfma_f32_16x16x32_bf16(F3_, bf0, acc[RB_ + 3][0], 0, 0, 0); \
        acc[RB_ + 3][1] = __builtin_amdgcn_mfma_f32_16x16x32_bf16(F3_, bf1, acc[RB_ + 3][1], 0, 0, 0); \
        acc[RB_ + 3][2] = __builtin_amdgcn_mfma_f32_16x16x32_bf16(F3_, bf2, acc[RB_ + 3][2], 0, 0, 0); \
        acc[RB_ + 3][3] = __builtin_amdgcn_mfma_f32_16x16x32_bf16(F3_, bf3, acc[RB_ + 3][3], 0, 0, 0); \
    } while (0)

// one phase-pair = phases A (m-low) + B (m-high) for parity P, k-half H
#define PAIR(P_, H_, S1_, G1_, S2_, G2_)                                        \
    do {                                                                        \
        bf16x8 bf0 = RD(LDSB(P_, H_), wn * 64 + 0 + rA);                        \
        bf16x8 bf1 = RD(LDSB(P_, H_), wn * 64 + 16 + rA);                       \
        bf16x8 bf2 = RD(LDSB(P_, H_), wn * 64 + 32 + rA);                       \
        bf16x8 bf3 = RD(LDSB(P_, H_), wn * 64 + 48 + rA);                       \
        bf16x8 af0 = RD(LDSA(P_, H_), wm * 128 + 0 + rA);                       \
        bf16x8 af1 = RD(LDSA(P_, H_), wm * 128 + 16 + rA);                      \
        bf16x8 af2 = RD(LDSA(P_, H_), wm * 128 + 32 + rA);                      \
        bf16x8 af3 = RD(LDSA(P_, H_), wm * 128 + 48 + rA);                      \
        S1_; G1_;                                                               \
        SBAR; __builtin_amdgcn_s_barrier(); SBAR;                               \
        asm volatile("s_waitcnt lgkmcnt(0)" ::: "memory"); SBAR;                \
        __builtin_amdgcn_s_setprio(1);                                          \
        MFMA16(af0, af1, af2, af3, 0);                                          \
        __builtin_amdgcn_s_setprio(0); SBAR;                                    \
        __builtin_amdgcn_s_barrier(); SBAR;                                     \
        bf16x8 ag0 = RD(LDSA(P_, H_), wm * 128 + 64 + rA);                      \
        bf16x8 ag1 = RD(LDSA(P_, H_), wm * 128 + 80 + rA);                      \
        bf16x8 ag2 = RD(LDSA(P_, H_), wm * 128 + 96 + rA);                      \
        bf16x8 ag3 = RD(LDSA(P_, H_), wm * 128 + 112 + rA);                     \
        S2_; G2_;                                                               \
        SBAR; __builtin_amdgcn_s_barrier(); SBAR;                               \
        asm volatile("s_waitcnt lgkmcnt(0)" ::: "memory"); SBAR;                \
        __builtin_amdgcn_s_setprio(1);                                          \
        MFMA16(ag0, ag1, ag2, ag3, 4);                                          \
        __builtin_amdgcn_s_setprio(0); SBAR;                                    \
        __builtin_amdgcn_s_barrier(); SBAR;                                     \
    } while (0)

    // prologue: tile0 both halves + tile1 kh0; retire all but tile1-kh0 (4 loads)
    STA(0, 0, 0); STB(0, 0, 0);
    STA(0, 1, 0); STB(0, 1, 0);
    STA(1, 0, 1); STB(1, 0, 1);
    GATE(4); SBAR;
    __builtin_amdgcn_s_barrier(); SBAR;

    const int NITER = K / 128;
    for (int i = 0; i < NITER - 1; ++i) {
        const int t0 = 2 * i;
        PAIR(0, 0, { STA(1, 1, t0 + 1); STB(1, 1, t0 + 1); }, (void)0, (void)0, (void)0);
        PAIR(0, 1, STA(0, 0, t0 + 2), (void)0, STB(0, 0, t0 + 2), GATE(4));
        PAIR(1, 0, { STA(0, 1, t0 + 2); STB(0, 1, t0 + 2); }, (void)0, (void)0, (void)0);
        PAIR(1, 1, STA(1, 0, t0 + 3), (void)0, STB(1, 0, t0 + 3), GATE(4));
    }
    // peeled last iteration: no future stages; vmcnt(0) at ph4 retires
    // both tile(last)-kh0 (prev ph7/8) and tile(last)-kh1 (this ph1).
    {
        const int tl = 2 * (NITER - 1);
        PAIR(0, 0, { STA(1, 1, tl + 1); STB(1, 1, tl + 1); }, (void)0, (void)0, (void)0);
        PAIR(0, 1, (void)0, (void)0, (void)0, GATE(0));
        PAIR(1, 0, (void)0, (void)0, (void)0, (void)0);
        PAIR(1, 1, (void)0, (void)0, (void)0, (void)0);
    }

#undef PAIR
#undef MFMA16
#undef STB
#undef STA
#undef GATE
#undef SBAR
#undef RD
#undef LDSB
#undef LDSA

    // epilogue: frag layout col=lane&15, row=(lane>>4)*4+r
    const int cr0 = brow + wm * 128;
    const int cc0 = bcol + wn * 64;
#pragma unroll
    for (int ni = 0; ni < 4; ++ni) {
        const int col = cc0 + ni * 16 + (lane & 15);
        const float bv = Bi[col];
#pragma unroll
        for (int mi = 0; mi < 8; ++mi) {
#pragma unroll
            for (int r = 0; r < 4; ++r) {
                const int row = cr0 + mi * 16 + (lane >> 4) * 4 + r;
                Out[(size_t)row * N + col] = acc[mi][ni][r] + bv;
            }
        }
    }
}

// ---------------- fallback: fused kernel (ws too small / odd shapes) ----------------
__global__ __launch_bounds__(256, 3)
void awq_gemm_fused(const float* __restrict__ X,
                    const int* __restrict__ QW,
                    const int* __restrict__ QZ,
                    const float* __restrict__ S,
                    const float* __restrict__ Bi,
                    float* __restrict__ Out,
                    int M, int N, int K) {
    const int PQ = K >> 3, NG = K >> 7, ZS = (NG + 7) >> 3;

    __shared__ __align__(16) __bf16 As[BM * BK];
    __shared__ __align__(16) __bf16 Bs[BN * BK];

    const int tid  = threadIdx.x;
    const int lane = tid & 63;
    const int wid  = tid >> 6;

    const int nwg = gridDim.x;
    int bid = blockIdx.x;
    if ((nwg & 7) == 0) {
        const int cpx = nwg >> 3;
        bid = (bid & 7) * cpx + (bid >> 3);
    }
    const int nbn  = N / BN;
    const int brow = (bid / nbn) * BM;
    const int bcol = (bid % nbn) * BN;

    const int wm = wid >> 1;
    const int wn = wid & 1;

    f32x4 acc[4][4];
#pragma unroll
    for (int i = 0; i < 4; ++i)
#pragma unroll
        for (int j = 0; j < 4; ++j)
            acc[i][j] = {0.f, 0.f, 0.f, 0.f};

    int arow[4], acch[4];
#pragma unroll
    for (int it = 0; it < 4; ++it) {
        const int idx = it * 256 + tid;
        arow[it] = idx >> 3;
        acch[it] = idx & 7;
    }

    const int rb    = tid >> 1;
    const int bhalf = tid & 1;
    const int og    = bcol + rb;
    const int* qwrow = QW + (size_t)og * PQ;
    const int* qzrow = QZ + (size_t)og * ZS;
    const float* srow = S + (size_t)og * NG;

    for (int kk = 0; kk < K; kk += BK) {
        bf16x8 areg[4];
#pragma unroll
        for (int it = 0; it < 4; ++it) {
            const float* gx = X + (size_t)(brow + arow[it]) * K + kk + acch[it] * 8;
            const float4 x0 = *(const float4*)gx;
            const float4 x1 = *(const float4*)(gx + 4);
            areg[it][0] = (__bf16)x0.x; areg[it][1] = (__bf16)x0.y;
            areg[it][2] = (__bf16)x0.z; areg[it][3] = (__bf16)x0.w;
            areg[it][4] = (__bf16)x1.x; areg[it][5] = (__bf16)x1.y;
            areg[it][6] = (__bf16)x1.z; areg[it][7] = (__bf16)x1.w;
        }

        const int4 qv = *(const int4*)(qwrow + (kk >> 3) + bhalf * 4);
        const int g  = kk >> 7;
        const int zq = (qzrow[g >> 3] >> ((g & 7) * 4)) & 15;
        const float sf = srow[g];
        const float zs = (float)zq * sf;
        const int vs[4] = {qv.x, qv.y, qv.z, qv.w};
        bf16x8 wregs[4];
#pragma unroll
        for (int w = 0; w < 4; ++w) {
            const int v = vs[w];
#pragma unroll
            for (int j = 0; j < 8; ++j) {
                const float q = (float)((v >> (4 * j)) & 15);
                wregs[w][j] = (__bf16)(q * sf - zs);
            }
        }

#pragma unroll
        for (int it = 0; it < 4; ++it) {
            const int cs = acch[it] ^ (arow[it] & 7);
            *((bf16x8*)(As + (size_t)arow[it] * BK + cs * 8)) = areg[it];
        }
#pragma unroll
        for (int w = 0; w < 4; ++w) {
            const int cs = (bhalf * 4 + w) ^ (rb & 7);
            *((bf16x8*)(Bs + (size_t)rb * BK + cs * 8)) = wregs[w];
        }

        __syncthreads();

#pragma unroll
        for (int ks = 0; ks < 2; ++ks) {
            bf16x8 af[4], bfr[4];
#pragma unroll
            for (int mi = 0; mi < 4; ++mi) {
                const int row = wm * 64 + mi * 16 + (lane & 15);
                const int cs  = (ks * 4 + (lane >> 4)) ^ (row & 7);
                af[mi] = *((const bf16x8*)(As + (size_t)row * BK + cs * 8));
            }
#pragma unroll
            for (int ni = 0; ni < 4; ++ni) {
                const int row = wn * 64 + ni * 16 + (lane & 15);
                const int cs  = (ks * 4 + (lane >> 4)) ^ (row & 7);
                bfr[ni] = *((const bf16x8*)(Bs + (size_t)row * BK + cs * 8));
            }
#pragma unroll
            for (int mi = 0; mi < 4; ++mi)
#pragma unroll
                for (int ni = 0; ni < 4; ++ni)
                    acc[mi][ni] = __builtin_amdgcn_mfma_f32_16x16x32_bf16(
                        af[mi], bfr[ni], acc[mi][ni], 0, 0, 0);
        }
        __syncthreads();
    }

    const int cr0 = brow + wm * 64;
    const int cc0 = bcol + wn * 64;
#pragma unroll
    for (int ni = 0; ni < 4; ++ni) {
        const int col = cc0 + ni * 16 + (lane & 15);
        const float bv = Bi[col];
#pragma unroll
        for (int mi = 0; mi < 4; ++mi) {
#pragma unroll
            for (int r = 0; r < 4; ++r) {
                const int row = cr0 + mi * 16 + (lane >> 4) * 4 + r;
                Out[(size_t)row * N + col] = acc[mi][ni][r] + bv;
            }
        }
    }
}

extern "C" void kernel_launch(void* const* d_in, const int* in_sizes, int n_in,
                              void* d_out, int out_size, void* d_ws, size_t ws_size,
                              hipStream_t stream) {
    const float* X  = (const float*)d_in[0];
    const int*   QW = (const int*)d_in[1];
    const int*   QZ = (const int*)d_in[2];
    const float* S  = (const float*)d_in[3];
    const float* Bi = (const float*)d_in[4];
    float*       Out = (float*)d_out;

    const int O = in_sizes[4];           // 11008
    const int K = in_sizes[1] / O * 8;   // 4096
    const int M = in_sizes[0] / K;       // 8192

    const size_t szX = (size_t)M * K * sizeof(__bf16);   // 64 MiB
    const size_t szW = (size_t)O * K * sizeof(__bf16);   // 86 MiB

    const bool shapes_ok = (M % 256 == 0) && (O % 256 == 0) &&
                           (K % 128 == 0) && (K / 128 >= 2);

    if (ws_size >= szX + szW && shapes_ok) {
        __bf16* Xb = (__bf16*)d_ws;
        __bf16* Wb = (__bf16*)((char*)d_ws + szX);
        const size_t n8 = (size_t)M * K / 8;
        cvt_x<<<2048, 256, 0, stream>>>(X, Xb, n8);
        dequant_w<<<O, K / 32, 0, stream>>>(QW, QZ, S, Wb, O, K);
        const int grid = (M / 256) * (O / 256);   // 32*43 = 1376
        gemm_8ph<<<grid, 512, 0, stream>>>(Xb, Wb, Bi, Out, M, O, K);
    } else {
        const int grid = (M / BM) * (O / BN);
        awq_gemm_fused<<<grid, 256, 0, stream>>>(X, QW, QZ, S, Bi, Out, M, O, K);
    }
}

// Round 9
// 716.569 us; speedup vs baseline: 1.3699x; 1.3699x over previous
//
#include <hip/hip_runtime.h>
#include <hip/hip_bf16.h>
#include <stdint.h>

typedef __attribute__((ext_vector_type(8))) __bf16 bf16x8;
typedef __attribute__((ext_vector_type(4))) float f32x4;
typedef __attribute__((ext_vector_type(4))) int   i32x4;

#define BM 128
#define BN 128
#define BK 64

// i8 GEMM geometry: 256(M) x 128(N) block, K-step 128 (= one AWQ group), ring-3 LDS
#define IBM 256
#define IBN 128
#define IBK 128

__device__ inline void gload_lds16(const void* g, void* l) {
    __builtin_amdgcn_global_load_lds(
        (const __attribute__((address_space(1))) uint32_t*)g,
        (__attribute__((address_space(3))) uint32_t*)l, 16, 0, 0);
}

// ---------------- pass 1a: X f32 -> per-row int8 + scale ----------------
__global__ __launch_bounds__(256)
void quant_x(const float* __restrict__ X, int8_t* __restrict__ Xq,
             float* __restrict__ sx, int K) {
    const int row = blockIdx.x;
    const int tid = threadIdx.x;
    const float* base = X + (size_t)row * K;
    __shared__ float wred[4];

    float am = 0.f;
    for (int b = tid * 16; b < K; b += 256 * 16) {
#pragma unroll
        for (int c = 0; c < 4; ++c) {
            const float4 v = *(const float4*)(base + b + c * 4);
            am = fmaxf(am, fmaxf(fmaxf(fabsf(v.x), fabsf(v.y)),
                                 fmaxf(fabsf(v.z), fabsf(v.w))));
        }
    }
#pragma unroll
    for (int off = 32; off >= 1; off >>= 1)
        am = fmaxf(am, __shfl_xor(am, off));
    if ((tid & 63) == 0) wred[tid >> 6] = am;
    __syncthreads();
    am = fmaxf(fmaxf(wred[0], wred[1]), fmaxf(wred[2], wred[3]));

    const float inv = am > 0.f ? 127.f / am : 0.f;
    for (int b = tid * 16; b < K; b += 256 * 16) {
        int w[4];
#pragma unroll
        for (int c = 0; c < 4; ++c) {
            const float4 v = *(const float4*)(base + b + c * 4);
            const int b0 = __float2int_rn(v.x * inv) & 0xFF;
            const int b1 = __float2int_rn(v.y * inv) & 0xFF;
            const int b2 = __float2int_rn(v.z * inv) & 0xFF;
            const int b3 = __float2int_rn(v.w * inv) & 0xFF;
            w[c] = b0 | (b1 << 8) | (b2 << 16) | (b3 << 24);
        }
        *(int4*)(Xq + (size_t)row * K + b) = make_int4(w[0], w[1], w[2], w[3]);
    }
    if (tid == 0) sx[row] = am > 0.f ? am / 127.f : 0.f;
}

// ---------------- pass 1b: W -> int8 (q - z), exact ----------------
__global__ __launch_bounds__(128)
void quant_w(const int* __restrict__ QW, const int* __restrict__ QZ,
             int8_t* __restrict__ Wq, int N, int K) {
    const int PQ = K >> 3, NG = K >> 7, ZS = (NG + 7) >> 3;
    const int o = blockIdx.x;
    const int c = threadIdx.x;            // 0..K/32-1
    const int g = c >> 2;
    const int zq = (QZ[(size_t)o * ZS + (g >> 3)] >> ((g & 7) * 4)) & 15;
    const int4 qv = *(const int4*)(QW + (size_t)o * PQ + c * 4);
    const int vs[4] = {qv.x, qv.y, qv.z, qv.w};
    int words[8];
#pragma unroll
    for (int w = 0; w < 4; ++w) {
        const int v = vs[w];
        int w0 = 0, w1 = 0;
#pragma unroll
        for (int j = 0; j < 4; ++j)
            w0 |= ((((v >> (4 * j)) & 15) - zq) & 0xFF) << (8 * j);
#pragma unroll
        for (int j = 0; j < 4; ++j)
            w1 |= ((((v >> (4 * (j + 4))) & 15) - zq) & 0xFF) << (8 * j);
        words[w * 2] = w0; words[w * 2 + 1] = w1;
    }
    int8_t* dst = Wq + (size_t)o * K + c * 32;
    *(int4*)dst        = make_int4(words[0], words[1], words[2], words[3]);
    *(int4*)(dst + 16) = make_int4(words[4], words[5], words[6], words[7]);
}

// ---------------- pass 1c: scales [O][NG] f32 -> [NG][O] ----------------
__global__ __launch_bounds__(256)
void tr_s(const float* __restrict__ S, float* __restrict__ St, int N, int NG) {
    const int idx = blockIdx.x * 256 + threadIdx.x;
    if (idx >= N * NG) return;
    const int g = idx / N, o = idx % N;
    St[idx] = S[(size_t)o * NG + g];
}

// ---------------- pass 2: i8 GEMM with per-group f32 scale merge ----------------
// 512 thr = 8 waves (4 wm x 2 wn), wave tile 64x64 = 4x4 frags of 16x16.
// mfma_i32_16x16x64_i8: per tile (K=128 = one group) 2 ksteps; i32 acc exact;
// facc[mi][ni] += (float)iacc * s[o,g] at tile end; out = sx[row]*facc + bias.
// LDS ring-3 x (A 256x128 i8 @ +0, B 128x128 @ +32768) = 144 KB.
// Chunk-XOR swizzle c_lds = c_g ^ (row&7), pre-swizzled global src (r6: 0 conflicts).
// vmcnt FIFO (audited): per tile issues [4 scale loads][6 stage(t+2) loads];
// CVT gate vmcnt(6) retires prev stage + own scales, leaves next stage in flight.
// Never drains to 0 until the 2-tile tail.
__global__ __launch_bounds__(512, 2)
void gemm_i8(const int8_t* __restrict__ Aq, const float* __restrict__ sx,
             const int8_t* __restrict__ Bq, const float* __restrict__ St,
             const float* __restrict__ Bi, float* __restrict__ Out,
             int M, int N, int K) {
    __shared__ __align__(16) char lds[3 * 49152];

    const int tid  = threadIdx.x;
    const int lane = tid & 63;
    const int wid  = tid >> 6;
    const int wm   = wid >> 1;   // 0..3
    const int wn   = wid & 1;    // 0..1

    int bid = blockIdx.x;
    {
        const int nwg = gridDim.x;
        if ((nwg & 7) == 0) {
            const int cpx = nwg >> 3;
            bid = (bid & 7) * cpx + (bid >> 3);
        }
    }
    const int nbm  = M / IBM;
    const int brow = (bid % nbm) * IBM;   // col-major tile order: B-panel L2-resident
    const int bcol = (bid / nbm) * IBN;

    // staging: A 2048 16B-slots (4/thread), B 1024 (2/thread).
    // slot s: row = s>>3, c_lds = s&7, global chunk c_g = c_lds ^ (row&7).
    int aro[4], acg[4], bro[2], bcg[2];
#pragma unroll
    for (int it = 0; it < 4; ++it) {
        const int s = it * 512 + tid;
        aro[it] = s >> 3; acg[it] = (s & 7) ^ ((s >> 3) & 7);
    }
#pragma unroll
    for (int it = 0; it < 2; ++it) {
        const int s = it * 512 + tid;
        bro[it] = s >> 3; bcg[it] = (s & 7) ^ ((s >> 3) & 7);
    }
    const int8_t* gA[4]; const int8_t* gB[2];
#pragma unroll
    for (int it = 0; it < 4; ++it) gA[it] = Aq + (size_t)(brow + aro[it]) * K + acg[it] * 16;
#pragma unroll
    for (int it = 0; it < 2; ++it) gB[it] = Bq + (size_t)(bcol + bro[it]) * K + bcg[it] * 16;

    const int rA15 = lane & 15;
    const int q4   = lane >> 4;

    f32x4 facc[4][4];
#pragma unroll
    for (int i = 0; i < 4; ++i)
#pragma unroll
        for (int j = 0; j < 4; ++j)
            facc[i][j] = {0.f, 0.f, 0.f, 0.f};

    const int NT = K / IBK;

#define SBAR __builtin_amdgcn_sched_barrier(0)
#define ABUF(RR_) (lds + (RR_) * 49152)
#define BBUF(RR_) (lds + (RR_) * 49152 + 32768)

#define STAGE(RR_, T_)                                                           \
    do {                                                                         \
        gload_lds16(gA[0] + (size_t)(T_) * IBK, ABUF(RR_) + (0 * 512 + wid * 64) * 16); \
        gload_lds16(gA[1] + (size_t)(T_) * IBK, ABUF(RR_) + (1 * 512 + wid * 64) * 16); \
        gload_lds16(gA[2] + (size_t)(T_) * IBK, ABUF(RR_) + (2 * 512 + wid * 64) * 16); \
        gload_lds16(gA[3] + (size_t)(T_) * IBK, ABUF(RR_) + (3 * 512 + wid * 64) * 16); \
        gload_lds16(gB[0] + (size_t)(T_) * IBK, BBUF(RR_) + (0 * 512 + wid * 64) * 16); \
        gload_lds16(gB[1] + (size_t)(T_) * IBK, BBUF(RR_) + (1 * 512 + wid * 64) * 16); \
    } while (0)

    // fragment read: row r, global chunk c = ks*4 + q4; byte = r*128 + (c^(r&7))*16
#define LDA(RR_, MI, KS)                                                         \
    (*(const i32x4*)(ABUF(RR_) + (wm * 64 + (MI) * 16 + rA15) * 128 +            \
                     ((((KS) * 4 + q4) ^ ((wm * 64 + (MI) * 16 + rA15) & 7)) * 16)))
#define LDB(RR_, NI, KS)                                                         \
    (*(const i32x4*)(BBUF(RR_) + (wn * 64 + (NI) * 16 + rA15) * 128 +            \
                     ((((KS) * 4 + q4) ^ ((wn * 64 + (NI) * 16 + rA15) & 7)) * 16)))

#define MFMA16(RR_, KS_, FIRST_)                                                 \
    do {                                                                         \
        i32x4 b0 = LDB(RR_, 0, KS_), b1 = LDB(RR_, 1, KS_);                      \
        i32x4 b2 = LDB(RR_, 2, KS_), b3 = LDB(RR_, 3, KS_);                      \
        i32x4 a0 = LDA(RR_, 0, KS_), a1 = LDA(RR_, 1, KS_);                      \
        i32x4 a2 = LDA(RR_, 2, KS_), a3 = LDA(RR_, 3, KS_);                      \
        asm volatile("s_waitcnt lgkmcnt(0)" ::: "memory"); SBAR;                 \
        __builtin_amdgcn_s_setprio(1);                                           \
        if (FIRST_) {                                                            \
            const i32x4 zz = {0, 0, 0, 0};                                       \
            iacc[0][0] = __builtin_amdgcn_mfma_i32_16x16x64_i8(a0, b0, zz, 0, 0, 0); \
            iacc[0][1] = __builtin_amdgcn_mfma_i32_16x16x64_i8(a0, b1, zz, 0, 0, 0); \
            iacc[0][2] = __builtin_amdgcn_mfma_i32_16x16x64_i8(a0, b2, zz, 0, 0, 0); \
            iacc[0][3] = __builtin_amdgcn_mfma_i32_16x16x64_i8(a0, b3, zz, 0, 0, 0); \
            iacc[1][0] = __builtin_amdgcn_mfma_i32_16x16x64_i8(a1, b0, zz, 0, 0, 0); \
            iacc[1][1] = __builtin_amdgcn_mfma_i32_16x16x64_i8(a1, b1, zz, 0, 0, 0); \
            iacc[1][2] = __builtin_amdgcn_mfma_i32_16x16x64_i8(a1, b2, zz, 0, 0, 0); \
            iacc[1][3] = __builtin_amdgcn_mfma_i32_16x16x64_i8(a1, b3, zz, 0, 0, 0); \
            iacc[2][0] = __builtin_amdgcn_mfma_i32_16x16x64_i8(a2, b0, zz, 0, 0, 0); \
            iacc[2][1] = __builtin_amdgcn_mfma_i32_16x16x64_i8(a2, b1, zz, 0, 0, 0); \
            iacc[2][2] = __builtin_amdgcn_mfma_i32_16x16x64_i8(a2, b2, zz, 0, 0, 0); \
            iacc[2][3] = __builtin_amdgcn_mfma_i32_16x16x64_i8(a2, b3, zz, 0, 0, 0); \
            iacc[3][0] = __builtin_amdgcn_mfma_i32_16x16x64_i8(a3, b0, zz, 0, 0, 0); \
            iacc[3][1] = __builtin_amdgcn_mfma_i32_16x16x64_i8(a3, b1, zz, 0, 0, 0); \
            iacc[3][2] = __builtin_amdgcn_mfma_i32_16x16x64_i8(a3, b2, zz, 0, 0, 0); \
            iacc[3][3] = __builtin_amdgcn_mfma_i32_16x16x64_i8(a3, b3, zz, 0, 0, 0); \
        } else {                                                                 \
            iacc[0][0] = __builtin_amdgcn_mfma_i32_16x16x64_i8(a0, b0, iacc[0][0], 0, 0, 0); \
            iacc[0][1] = __builtin_amdgcn_mfma_i32_16x16x64_i8(a0, b1, iacc[0][1], 0, 0, 0); \
            iacc[0][2] = __builtin_amdgcn_mfma_i32_16x16x64_i8(a0, b2, iacc[0][2], 0, 0, 0); \
            iacc[0][3] = __builtin_amdgcn_mfma_i32_16x16x64_i8(a0, b3, iacc[0][3], 0, 0, 0); \
            iacc[1][0] = __builtin_amdgcn_mfma_i32_16x16x64_i8(a1, b0, iacc[1][0], 0, 0, 0); \
            iacc[1][1] = __builtin_amdgcn_mfma_i32_16x16x64_i8(a1, b1, iacc[1][1], 0, 0, 0); \
            iacc[1][2] = __builtin_amdgcn_mfma_i32_16x16x64_i8(a1, b2, iacc[1][2], 0, 0, 0); \
            iacc[1][3] = __builtin_amdgcn_mfma_i32_16x16x64_i8(a1, b3, iacc[1][3], 0, 0, 0); \
            iacc[2][0] = __builtin_amdgcn_mfma_i32_16x16x64_i8(a2, b0, iacc[2][0], 0, 0, 0); \
            iacc[2][1] = __builtin_amdgcn_mfma_i32_16x16x64_i8(a2, b1, iacc[2][1], 0, 0, 0); \
            iacc[2][2] = __builtin_amdgcn_mfma_i32_16x16x64_i8(a2, b2, iacc[2][2], 0, 0, 0); \
            iacc[2][3] = __builtin_amdgcn_mfma_i32_16x16x64_i8(a2, b3, iacc[2][3], 0, 0, 0); \
            iacc[3][0] = __builtin_amdgcn_mfma_i32_16x16x64_i8(a3, b0, iacc[3][0], 0, 0, 0); \
            iacc[3][1] = __builtin_amdgcn_mfma_i32_16x16x64_i8(a3, b1, iacc[3][1], 0, 0, 0); \
            iacc[3][2] = __builtin_amdgcn_mfma_i32_16x16x64_i8(a3, b2, iacc[3][2], 0, 0, 0); \
            iacc[3][3] = __builtin_amdgcn_mfma_i32_16x16x64_i8(a3, b3, iacc[3][3], 0, 0, 0); \
        }                                                                        \
        __builtin_amdgcn_s_setprio(0); SBAR;                                     \
    } while (0)

#define TILE(R_, T_, TOPSTR_, CVTSTR_, STG_)                                     \
    do {                                                                         \
        asm volatile("s_waitcnt vmcnt(" TOPSTR_ ")" ::: "memory"); SBAR;         \
        __builtin_amdgcn_s_barrier(); SBAR;                                      \
        const size_t so = (size_t)(T_) * N + bcol + wn * 64 + rA15;              \
        const float sv0 = St[so +  0], sv1 = St[so + 16];                        \
        const float sv2 = St[so + 32], sv3 = St[so + 48];                        \
        SBAR;                                                                    \
        STG_;                                                                    \
        SBAR;                                                                    \
        i32x4 iacc[4][4];                                                        \
        MFMA16(R_, 0, true);                                                     \
        MFMA16(R_, 1, false);                                                    \
        asm volatile("s_waitcnt vmcnt(" CVTSTR_ ")" ::: "memory"); SBAR;         \
        _Pragma("unroll")                                                        \
        for (int mi = 0; mi < 4; ++mi) {                                         \
            _Pragma("unroll")                                                    \
            for (int j = 0; j < 4; ++j) {                                        \
                facc[mi][0][j] += (float)iacc[mi][0][j] * sv0;                   \
                facc[mi][1][j] += (float)iacc[mi][1][j] * sv1;                   \
                facc[mi][2][j] += (float)iacc[mi][2][j] * sv2;                   \
                facc[mi][3][j] += (float)iacc[mi][3][j] * sv3;                   \
            }                                                                    \
        }                                                                        \
    } while (0)

    // prologue: 2 tiles in flight
    STAGE(0, 0);
    STAGE(1, 1);

    for (int t = 0; t < NT - 2; ++t) {
        const int r = t % 3;
        const int r2 = (t + 2) % 3;
        TILE(r, t, "6", "6", STAGE(r2, t + 2));
    }
    TILE(((NT - 2) % 3), NT - 2, "6", "0", (void)0);
    TILE(((NT - 1) % 3), NT - 1, "0", "0", (void)0);

#undef TILE
#undef MFMA16
#undef LDB
#undef LDA
#undef STAGE
#undef BBUF
#undef ABUF
#undef SBAR

    // epilogue: C frag col=lane&15, row=(lane>>4)*4+r; out = sx[row]*acc + bias
    const int cr0 = brow + wm * 64;
    const int cc0 = bcol + wn * 64;
#pragma unroll
    for (int ni = 0; ni < 4; ++ni) {
        const int col = cc0 + ni * 16 + rA15;
        const float bv = Bi[col];
#pragma unroll
        for (int mi = 0; mi < 4; ++mi) {
#pragma unroll
            for (int r = 0; r < 4; ++r) {
                const int row = cr0 + mi * 16 + q4 * 4 + r;
                Out[(size_t)row * N + col] = sx[row] * facc[mi][ni][r] + bv;
            }
        }
    }
}

// ---------------- fallback: fused kernel (ws too small / odd shapes) ----------------
__global__ __launch_bounds__(256, 3)
void awq_gemm_fused(const float* __restrict__ X,
                    const int* __restrict__ QW,
                    const int* __restrict__ QZ,
                    const float* __restrict__ S,
                    const float* __restrict__ Bi,
                    float* __restrict__ Out,
                    int M, int N, int K) {
    const int PQ = K >> 3, NG = K >> 7, ZS = (NG + 7) >> 3;

    __shared__ __align__(16) __bf16 As[BM * BK];
    __shared__ __align__(16) __bf16 Bs[BN * BK];

    const int tid  = threadIdx.x;
    const int lane = tid & 63;
    const int wid  = tid >> 6;

    const int nwg = gridDim.x;
    int bid = blockIdx.x;
    if ((nwg & 7) == 0) {
        const int cpx = nwg >> 3;
        bid = (bid & 7) * cpx + (bid >> 3);
    }
    const int nbn  = N / BN;
    const int brow = (bid / nbn) * BM;
    const int bcol = (bid % nbn) * BN;

    const int wm = wid >> 1;
    const int wn = wid & 1;

    f32x4 acc[4][4];
#pragma unroll
    for (int i = 0; i < 4; ++i)
#pragma unroll
        for (int j = 0; j < 4; ++j)
            acc[i][j] = {0.f, 0.f, 0.f, 0.f};

    int arow[4], acch[4];
#pragma unroll
    for (int it = 0; it < 4; ++it) {
        const int idx = it * 256 + tid;
        arow[it] = idx >> 3;
        acch[it] = idx & 7;
    }

    const int rb    = tid >> 1;
    const int bhalf = tid & 1;
    const int og    = bcol + rb;
    const int* qwrow = QW + (size_t)og * PQ;
    const int* qzrow = QZ + (size_t)og * ZS;
    const float* srow = S + (size_t)og * NG;

    for (int kk = 0; kk < K; kk += BK) {
        bf16x8 areg[4];
#pragma unroll
        for (int it = 0; it < 4; ++it) {
            const float* gx = X + (size_t)(brow + arow[it]) * K + kk + acch[it] * 8;
            const float4 x0 = *(const float4*)gx;
            const float4 x1 = *(const float4*)(gx + 4);
            areg[it][0] = (__bf16)x0.x; areg[it][1] = (__bf16)x0.y;
            areg[it][2] = (__bf16)x0.z; areg[it][3] = (__bf16)x0.w;
            areg[it][4] = (__bf16)x1.x; areg[it][5] = (__bf16)x1.y;
            areg[it][6] = (__bf16)x1.z; areg[it][7] = (__bf16)x1.w;
        }

        const int4 qv = *(const int4*)(qwrow + (kk >> 3) + bhalf * 4);
        const int g  = kk >> 7;
        const int zq = (qzrow[g >> 3] >> ((g & 7) * 4)) & 15;
        const float sf = srow[g];
        const float zs = (float)zq * sf;
        const int vs[4] = {qv.x, qv.y, qv.z, qv.w};
        bf16x8 wregs[4];
#pragma unroll
        for (int w = 0; w < 4; ++w) {
            const int v = vs[w];
#pragma unroll
            for (int j = 0; j < 8; ++j) {
                const float q = (float)((v >> (4 * j)) & 15);
                wregs[w][j] = (__bf16)(q * sf - zs);
            }
        }

#pragma unroll
        for (int it = 0; it < 4; ++it) {
            const int cs = acch[it] ^ (arow[it] & 7);
            *((bf16x8*)(As + (size_t)arow[it] * BK + cs * 8)) = areg[it];
        }
#pragma unroll
        for (int w = 0; w < 4; ++w) {
            const int cs = (bhalf * 4 + w) ^ (rb & 7);
            *((bf16x8*)(Bs + (size_t)rb * BK + cs * 8)) = wregs[w];
        }

        __syncthreads();

#pragma unroll
        for (int ks = 0; ks < 2; ++ks) {
            bf16x8 af[4], bfr[4];
#pragma unroll
            for (int mi = 0; mi < 4; ++mi) {
                const int row = wm * 64 + mi * 16 + (lane & 15);
                const int cs  = (ks * 4 + (lane >> 4)) ^ (row & 7);
                af[mi] = *((const bf16x8*)(As + (size_t)row * BK + cs * 8));
            }
#pragma unroll
            for (int ni = 0; ni < 4; ++ni) {
                const int row = wn * 64 + ni * 16 + (lane & 15);
                const int cs  = (ks * 4 + (lane >> 4)) ^ (row & 7);
                bfr[ni] = *((const bf16x8*)(Bs + (size_t)row * BK + cs * 8));
            }
#pragma unroll
            for (int mi = 0; mi < 4; ++mi)
#pragma unroll
                for (int ni = 0; ni < 4; ++ni)
                    acc[mi][ni] = __builtin_amdgcn_mfma_f32_16x16x32_bf16(
                        af[mi], bfr[ni], acc[mi][ni], 0, 0, 0);
        }
        __syncthreads();
    }

    const int cr0 = brow + wm * 64;
    const int cc0 = bcol + wn * 64;
#pragma unroll
    for (int ni = 0; ni < 4; ++ni) {
        const int col = cc0 + ni * 16 + (lane & 15);
        const float bv = Bi[col];
#pragma unroll
        for (int mi = 0; mi < 4; ++mi) {
#pragma unroll
            for (int r = 0; r < 4; ++r) {
                const int row = cr0 + mi * 16 + (lane >> 4) * 4 + r;
                Out[(size_t)row * N + col] = acc[mi][ni][r] + bv;
            }
        }
    }
}

extern "C" void kernel_launch(void* const* d_in, const int* in_sizes, int n_in,
                              void* d_out, int out_size, void* d_ws, size_t ws_size,
                              hipStream_t stream) {
    const float* X  = (const float*)d_in[0];
    const int*   QW = (const int*)d_in[1];
    const int*   QZ = (const int*)d_in[2];
    const float* S  = (const float*)d_in[3];
    const float* Bi = (const float*)d_in[4];
    float*       Out = (float*)d_out;

    const int O = in_sizes[4];           // 11008
    const int K = in_sizes[1] / O * 8;   // 4096
    const int M = in_sizes[0] / K;       // 8192
    const int NG = K / 128;

    // ws layout: Xq [M*K i8] | sx [M f32] | Wq [O*K i8] | St [NG*O f32]
    const size_t oXq = 0;
    const size_t oSx = (size_t)M * K;
    const size_t oWq = oSx + (size_t)M * 4;
    const size_t oSt = oWq + (size_t)O * K;
    const size_t need = oSt + (size_t)NG * O * 4;

    const bool shapes_ok = (M % IBM == 0) && (O % IBN == 0) &&
                           (K % IBK == 0) && (K / IBK >= 4) &&
                           (oWq % 16 == 0) && (oSt % 16 == 0);

    if (ws_size >= need && shapes_ok) {
        int8_t* Xq = (int8_t*)d_ws + oXq;
        float*  sx = (float*)((char*)d_ws + oSx);
        int8_t* Wq = (int8_t*)d_ws + oWq;
        float*  St = (float*)((char*)d_ws + oSt);
        quant_x<<<M, 256, 0, stream>>>(X, Xq, sx, K);
        quant_w<<<O, K / 32, 0, stream>>>(QW, QZ, Wq, O, K);
        tr_s<<<(O * NG + 255) / 256, 256, 0, stream>>>(S, St, O, NG);
        const int grid = (M / IBM) * (O / IBN);   // 32*86 = 2752
        gemm_i8<<<grid, 512, 0, stream>>>(Xq, sx, Wq, St, Bi, Out, M, O, K);
    } else {
        const int grid = (M / BM) * (O / BN);
        awq_gemm_fused<<<grid, 256, 0, stream>>>(X, QW, QZ, S, Bi, Out, M, O, K);
    }
}